// Round 4
// baseline (2963.932 us; speedup 1.0000x reference)
//
#include <hip/hip_runtime.h>

#define N_ROWS 32768

// ================================================================ threefry
__device__ __forceinline__ unsigned rotl32(unsigned x, unsigned r) {
  return (x << r) | (x >> (32u - r));
}
__device__ __forceinline__ void tf_round(unsigned &x0, unsigned &x1, unsigned r) {
  x0 += x1; x1 = rotl32(x1, r); x1 ^= x0;
}

// jax.random.bernoulli(key(42), 0.1, (64,)) under jax_threefry_partitionable:
// per element j: threefry2x32(key=(0,42), counts=(hi=0, lo=j)) -> (y0,y1),
// bits = y0 ^ y1; u = bitcast((bits>>9)|0x3f800000)-1; mask = u < 0.1.
__global__ void mask_kernel(float* __restrict__ mask) {
  int j = threadIdx.x;
  if (j >= 64) return;
  const unsigned k0 = 0u, k1 = 42u;
  const unsigned k2 = 0x1BD11BDAu ^ k0 ^ k1;
  unsigned x0 = 0u;              // counts_hi = 0
  unsigned x1 = (unsigned)j;     // counts_lo = j
  x0 += k0; x1 += k1;
  tf_round(x0, x1, 13); tf_round(x0, x1, 15); tf_round(x0, x1, 26); tf_round(x0, x1, 6);
  x0 += k1; x1 += k2 + 1u;
  tf_round(x0, x1, 17); tf_round(x0, x1, 29); tf_round(x0, x1, 16); tf_round(x0, x1, 24);
  x0 += k2; x1 += k0 + 2u;
  tf_round(x0, x1, 13); tf_round(x0, x1, 15); tf_round(x0, x1, 26); tf_round(x0, x1, 6);
  x0 += k0; x1 += k1 + 3u;
  tf_round(x0, x1, 17); tf_round(x0, x1, 29); tf_round(x0, x1, 16); tf_round(x0, x1, 24);
  x0 += k1; x1 += k2 + 4u;
  tf_round(x0, x1, 13); tf_round(x0, x1, 15); tf_round(x0, x1, 26); tf_round(x0, x1, 6);
  x0 += k2; x1 += k0 + 5u;
  unsigned bits = x0 ^ x1;
  float u = __uint_as_float((bits >> 9) | 0x3f800000u) - 1.0f;
  mask[j] = (u < 0.1f) ? 1.0f : 0.0f;
}

// ------------------------------------------------- numpy-pairwise ||row||^2
__global__ void norme_kernel(const float* __restrict__ cb, float* __restrict__ nE) {
#pragma clang fp contract(off)
  int k = blockIdx.x * blockDim.x + threadIdx.x;  // 0..8191
  const float* r = cb + (size_t)k * 256;
  float halves[2];
#pragma unroll
  for (int h = 0; h < 2; h++) {
    float a[8];
#pragma unroll
    for (int j = 0; j < 8; j++) a[j] = 0.0f;
    for (int t = 0; t < 16; t++) {
      float4 v0 = *(const float4*)&r[h * 128 + 8 * t];
      float4 v1 = *(const float4*)&r[h * 128 + 8 * t + 4];
      a[0] = a[0] + v0.x * v0.x; a[1] = a[1] + v0.y * v0.y;
      a[2] = a[2] + v0.z * v0.z; a[3] = a[3] + v0.w * v0.w;
      a[4] = a[4] + v1.x * v1.x; a[5] = a[5] + v1.y * v1.y;
      a[6] = a[6] + v1.z * v1.z; a[7] = a[7] + v1.w * v1.w;
    }
    halves[h] = ((a[0] + a[1]) + (a[2] + a[3])) + ((a[4] + a[5]) + (a[6] + a[7]));
  }
  nE[k] = halves[0] + halves[1];
}

__global__ void rownorm_kernel(const float* __restrict__ R, float* __restrict__ rr) {
#pragma clang fp contract(off)
  int tid = threadIdx.x;
  int row = blockIdx.x * 64 + (tid >> 2);
  int q = tid & 3;
  int h = q >> 1;
  int j0 = (q & 1) << 2;
  const float* p = R + (size_t)row * 256 + h * 128 + j0;
  float a[4] = {0.f, 0.f, 0.f, 0.f};
  for (int t = 0; t < 16; t++) {
    float4 v = *(const float4*)&p[8 * t];
    a[0] = a[0] + v.x * v.x; a[1] = a[1] + v.y * v.y;
    a[2] = a[2] + v.z * v.z; a[3] = a[3] + v.w * v.w;
  }
  float s = (a[0] + a[1]) + (a[2] + a[3]);
  float half = s + __shfl_xor(s, 1, 4);
  float tot = half + __shfl_xor(half, 2, 4);
  if (q == 0) rr[row] = tot;
}

// ---------------------------------------------------------------- BN prep
__global__ void bnprep_kernel(const double* __restrict__ psum, const double* __restrict__ psq,
                              const float* __restrict__ g, const float* __restrict__ bt,
                              float* __restrict__ a, float* __restrict__ c, int F) {
  int f = blockIdx.x * blockDim.x + threadIdx.x;
  if (f >= F) return;
  double s = 0.0, q = 0.0;
  const double* ps = psum + (size_t)f * 512;
  const double* pq = psq + (size_t)f * 512;
  for (int b = 0; b < 512; b++) { s += ps[b]; q += pq[b]; }
  double mu  = s * (1.0 / 32768.0);
  double var = q * (1.0 / 32768.0) - mu * mu;
  double inv = (double)g[f] / sqrt(var + 1e-5);
  a[f] = (float)inv;
  c[f] = (float)((double)bt[f] - mu * inv);
}

// ---------------------------------------------------------------- GEMM (enc/dec)
// out[N,F] = Aeff[N,K] @ W[K,F] + bias
// MODE: 0 = mask+pos prologue, 1 = relu(A*a+c), 2 = plain, 3 = A+p0+p1+A3 (zq fuse)
template <int MODE, int STATS>
__global__ __launch_bounds__(256)
void gemm64(const float* __restrict__ A, const float* __restrict__ W,
            const float* __restrict__ bias, const float* __restrict__ p0,
            const float* __restrict__ p1, const float* __restrict__ A3,
            float* __restrict__ out,
            double* __restrict__ psum, double* __restrict__ psq, int K, int F) {
  __shared__ float As[16][68];
  __shared__ float Bs[16][68];
  __shared__ double psumS[4][64];
  __shared__ double psqS[4][64];
  const int tid = threadIdx.x;
  const int row0 = blockIdx.y << 6;
  const int col0 = blockIdx.x << 6;
  const int ty = tid >> 4, tx = tid & 15;
  const int ar = tid >> 2, aq = (tid & 3) << 2;
  const int bk = tid >> 4, bc = (tid & 15) << 2;
  float acc[4][4] = {};
  for (int k0 = 0; k0 < K; k0 += 16) {
    const size_t aoff = (size_t)(row0 + ar) * K + k0 + aq;
    float4 av = *(const float4*)&A[aoff];
    float4 bv = *(const float4*)&W[(size_t)(k0 + bk) * F + col0 + bc];
    float a4[4] = { av.x, av.y, av.z, av.w };
    if (MODE == 0) {
#pragma unroll
      for (int j = 0; j < 4; j++) {
        int gk = k0 + aq + j;
        float m = p0[gk];
        float v = (m != 0.0f || (row0 + ar) == 0) ? 0.0f : a4[j];
        a4[j] = v + p1[gk];
      }
    } else if (MODE == 1) {
#pragma unroll
      for (int j = 0; j < 4; j++) {
        int gk = k0 + aq + j;
        a4[j] = fmaxf(fmaf(a4[j], p0[gk], p1[gk]), 0.0f);
      }
    } else if (MODE == 3) {
      float4 v1 = *(const float4*)&p0[aoff];
      float4 v2 = *(const float4*)&p1[aoff];
      float4 v3 = *(const float4*)&A3[aoff];
      a4[0] = ((a4[0] + v1.x) + v2.x) + v3.x;
      a4[1] = ((a4[1] + v1.y) + v2.y) + v3.y;
      a4[2] = ((a4[2] + v1.z) + v2.z) + v3.z;
      a4[3] = ((a4[3] + v1.w) + v2.w) + v3.w;
    }
    __syncthreads();
#pragma unroll
    for (int j = 0; j < 4; j++) As[aq + j][ar] = a4[j];
    *(float4*)&Bs[bk][bc] = bv;
    __syncthreads();
#pragma unroll
    for (int kc = 0; kc < 16; kc++) {
      float4 a = *(const float4*)&As[kc][ty << 2];
      float4 b = *(const float4*)&Bs[kc][tx << 2];
      float a_[4] = { a.x, a.y, a.z, a.w };
      float b_[4] = { b.x, b.y, b.z, b.w };
#pragma unroll
      for (int i = 0; i < 4; i++)
#pragma unroll
        for (int j = 0; j < 4; j++)
          acc[i][j] = fmaf(a_[i], b_[j], acc[i][j]);
    }
  }
  float bj[4];
#pragma unroll
  for (int j = 0; j < 4; j++) bj[j] = bias[col0 + (tx << 2) + j];
  double sj[4] = {}, qj[4] = {};
#pragma unroll
  for (int i = 0; i < 4; i++) {
    float v[4];
#pragma unroll
    for (int j = 0; j < 4; j++) {
      v[j] = acc[i][j] + bj[j];
      if (STATS) {
        sj[j] += (double)v[j];
        qj[j] += (double)v[j] * (double)v[j];
      }
    }
    float4 vv = { v[0], v[1], v[2], v[3] };
    *(float4*)&out[(size_t)(row0 + (ty << 2) + i) * F + col0 + (tx << 2)] = vv;
  }
  if (STATS) {
#pragma unroll
    for (int j = 0; j < 4; j++) {
      sj[j] += __shfl_down(sj[j], 32);
      sj[j] += __shfl_down(sj[j], 16);
      qj[j] += __shfl_down(qj[j], 32);
      qj[j] += __shfl_down(qj[j], 16);
    }
    const int w = tid >> 6;
    if ((tid & 63) < 16) {
#pragma unroll
      for (int j = 0; j < 4; j++) {
        psumS[w][((tid & 15) << 2) + j] = sj[j];
        psqS[w][((tid & 15) << 2) + j] = qj[j];
      }
    }
    __syncthreads();
    if (tid < 64) {
      double ds = (psumS[0][tid] + psumS[1][tid]) + (psumS[2][tid] + psumS[3][tid]);
      double dq = (psqS[0][tid] + psqS[1][tid]) + (psqS[2][tid] + psqS[3][tid]);
      psum[(size_t)(col0 + tid) * 512 + blockIdx.y] = ds;
      psq[(size_t)(col0 + tid) * 512 + blockIdx.y] = dq;
    }
  }
}

// ---------------------------------------------------------------- quantize
__global__ __launch_bounds__(256)
void quantize_kernel(const float* __restrict__ R, const float* __restrict__ E,
                     const float* __restrict__ nE, const float* __restrict__ rr,
                     float* __restrict__ ce, float* __restrict__ resn) {
  __shared__ float As[16][68];
  __shared__ float Bs[16][260];
  __shared__ int s_idx[64];
  const int tid = threadIdx.x;
  const int row0 = blockIdx.x << 6;
  const int rt = tid >> 5;
  const int kt = tid & 31;
  const int sr = tid >> 2, sh = (tid & 3) << 2;
  float rrv[8];
#pragma unroll
  for (int i = 0; i < 8; i++) rrv[i] = rr[row0 + (rt << 3) + i];
  float bestD[8];
  int   bestI[8];
#pragma unroll
  for (int i = 0; i < 8; i++) { bestD[i] = 3.0e38f; bestI[i] = 0; }

  for (int kk = 0; kk < 2048; kk += 256) {
    float acc[8][8];
#pragma unroll
    for (int i = 0; i < 8; i++)
#pragma unroll
      for (int j = 0; j < 8; j++) acc[i][j] = 0.f;

    for (int c0 = 0; c0 < 256; c0 += 16) {
      float4 av = *(const float4*)&R[(size_t)(row0 + sr) * 256 + c0 + sh];
      float4 bv[4];
#pragma unroll
      for (int q = 0; q < 4; q++)
        bv[q] = *(const float4*)&E[(size_t)(kk + tid) * 256 + c0 + (q << 2)];
      __syncthreads();
      As[sh + 0][sr] = av.x; As[sh + 1][sr] = av.y;
      As[sh + 2][sr] = av.z; As[sh + 3][sr] = av.w;
#pragma unroll
      for (int q = 0; q < 4; q++) {
        Bs[(q << 2) + 0][tid] = bv[q].x; Bs[(q << 2) + 1][tid] = bv[q].y;
        Bs[(q << 2) + 2][tid] = bv[q].z; Bs[(q << 2) + 3][tid] = bv[q].w;
      }
      __syncthreads();
#pragma unroll
      for (int c = 0; c < 16; c++) {
        float4 aA = *(const float4*)&As[c][rt << 3];
        float4 aB = *(const float4*)&As[c][(rt << 3) + 4];
        float4 bA = *(const float4*)&Bs[c][kt << 3];
        float4 bB = *(const float4*)&Bs[c][(kt << 3) + 4];
        float a_[8] = { aA.x, aA.y, aA.z, aA.w, aB.x, aB.y, aB.z, aB.w };
        float b_[8] = { bA.x, bA.y, bA.z, bA.w, bB.x, bB.y, bB.z, bB.w };
#pragma unroll
        for (int i = 0; i < 8; i++)
#pragma unroll
          for (int j = 0; j < 8; j++)
            acc[i][j] = fmaf(a_[i], b_[j], acc[i][j]);
      }
    }
#pragma unroll
    for (int j = 0; j < 8; j++) {
      int kg = kk + (kt << 3) + j;
      float nn = nE[kg];
#pragma unroll
      for (int i = 0; i < 8; i++) {
        float t = rrv[i] - 2.0f * acc[i][j];
        float d = t + nn;
        if (d < bestD[i]) { bestD[i] = d; bestI[i] = kg; }
      }
    }
  }
#pragma unroll
  for (int i = 0; i < 8; i++) {
    float d = bestD[i]; int b = bestI[i];
#pragma unroll
    for (int off = 16; off >= 1; off >>= 1) {
      float d2 = __shfl_down(d, off, 32);
      int   b2 = __shfl_down(b, off, 32);
      if (d2 < d || (d2 == d && b2 < b)) { d = d2; b = b2; }
    }
    if (kt == 0) s_idx[(rt << 3) + i] = b;
  }
  __syncthreads();
  const int orow = tid >> 2;
  const int oc0 = (tid & 3) << 6;
  const int gr = row0 + orow;
  const int idx = s_idx[orow];
  const float* __restrict__ Er = E + (size_t)idx * 256;
  const float* __restrict__ Rr = R + (size_t)gr * 256;
  float* __restrict__ Cr = ce + (size_t)gr * 256;
  if (resn) {
    float* __restrict__ Nr = resn + (size_t)gr * 256;
    for (int c = oc0; c < oc0 + 64; c += 4) {
      float4 e = *(const float4*)&Er[c];
      float4 r = *(const float4*)&Rr[c];
      *(float4*)&Cr[c] = e;
      float4 dd = { r.x - e.x, r.y - e.y, r.z - e.z, r.w - e.w };
      *(float4*)&Nr[c] = dd;
    }
  } else {
    for (int c = oc0; c < oc0 + 64; c += 4) {
      float4 e = *(const float4*)&Er[c];
      *(float4*)&Cr[c] = e;
    }
  }
}

// ---------------------------------------------------------------- launch
extern "C" void kernel_launch(void* const* d_in, const int* in_sizes, int n_in,
                              void* d_out, int out_size, void* d_ws, size_t ws_size,
                              hipStream_t stream) {
  (void)in_sizes; (void)n_in; (void)out_size; (void)ws_size;
  const float* x     = (const float*)d_in[0];
  const float* pos   = (const float*)d_in[1];
  const float* e_w0  = (const float*)d_in[2];
  const float* e_b0  = (const float*)d_in[3];
  const float* e_g0  = (const float*)d_in[4];
  const float* e_bt0 = (const float*)d_in[5];
  const float* e_w1  = (const float*)d_in[6];
  const float* e_b1  = (const float*)d_in[7];
  const float* e_g1  = (const float*)d_in[8];
  const float* e_bt1 = (const float*)d_in[9];
  const float* e_w2  = (const float*)d_in[10];
  const float* e_b2  = (const float*)d_in[11];
  const float* cb    = (const float*)d_in[12];
  const float* d_w0  = (const float*)d_in[13];
  const float* d_b0  = (const float*)d_in[14];
  const float* d_g0  = (const float*)d_in[15];
  const float* d_bt0 = (const float*)d_in[16];
  const float* d_w1  = (const float*)d_in[17];
  const float* d_b1  = (const float*)d_in[18];
  const float* d_g1  = (const float*)d_in[19];
  const float* d_bt1 = (const float*)d_in[20];
  const float* d_w2  = (const float*)d_in[21];
  const float* d_b2  = (const float*)d_in[22];

  // ---------------- workspace layout (float offsets; ~13 MB total) ----------
  float* ws = (float*)d_ws;
  float* mask   = ws + 64;                         // 64
  float* aff    = ws + 128;                        // 1536
  float* nE     = ws + 1664;                       // 8192
  double* psum  = (double*)(ws + 16384);           // 131072 dbl
  double* psq   = (double*)(ws + 278528);          // 131072 dbl
  float* g1     = ws + 540672;                     // dec h1' [N,256]
  float* g0     = g1 + (size_t)N_ROWS * 256;       // dec h0' [N,128]
  float* rr     = g0 + (size_t)N_ROWS * 128;       // N

  float* e0a = aff + 0;    float* e0c = aff + 128;
  float* e1a = aff + 256;  float* e1c = aff + 512;
  float* d0a = aff + 768;  float* d0c = aff + 1024;
  float* d1a = aff + 1280; float* d1c = aff + 1408;

  // ---------------- output layout ----------------
  float* outp = (float*)d_out;
  float* xhat = outp;
  float* res0 = outp + (size_t)N_ROWS * 64;
  float* res1 = res0 + (size_t)N_ROWS * 256;
  float* res2 = res1 + (size_t)N_ROWS * 256;
  float* res3 = res2 + (size_t)N_ROWS * 256;
  float* ce0  = res0 + (size_t)4 * N_ROWS * 256;
  float* ce1  = ce0 + (size_t)N_ROWS * 256;
  float* ce2  = ce1 + (size_t)N_ROWS * 256;
  float* ce3  = ce2 + (size_t)N_ROWS * 256;

  // scratch overlays into not-yet-written output regions (lifetime-checked):
  float* h0 = ce2;   // enc h0 [N,128]; ce2 written at quantize stage 2
  float* h1 = ce3;   // enc h1 [N,256]; ce3 written at quantize stage 3

  mask_kernel<<<1, 64, 0, stream>>>(mask);
  norme_kernel<<<32, 256, 0, stream>>>(cb, nE);

  // encoder
  gemm64<0, 1><<<dim3(2, 512), 256, 0, stream>>>(x, e_w0, e_b0, mask, pos, nullptr,
                                                 h0, psum, psq, 64, 128);
  bnprep_kernel<<<1, 256, 0, stream>>>(psum, psq, e_g0, e_bt0, e0a, e0c, 128);
  gemm64<1, 1><<<dim3(4, 512), 256, 0, stream>>>(h0, e_w1, e_b1, e0a, e0c, nullptr,
                                                 h1, psum, psq, 128, 256);
  bnprep_kernel<<<1, 256, 0, stream>>>(psum, psq, e_g1, e_bt1, e1a, e1c, 256);
  gemm64<1, 0><<<dim3(4, 512), 256, 0, stream>>>(h1, e_w2, e_b2, e1a, e1c, nullptr,
                                                 res0, nullptr, nullptr, 256, 256);

  // residual VQ
  rownorm_kernel<<<512, 256, 0, stream>>>(res0, rr);
  quantize_kernel<<<512, 256, 0, stream>>>(res0, cb + (size_t)0 * 2048 * 256, nE + 0,
                                           rr, ce0, res1);
  rownorm_kernel<<<512, 256, 0, stream>>>(res1, rr);
  quantize_kernel<<<512, 256, 0, stream>>>(res1, cb + (size_t)1 * 2048 * 256, nE + 2048,
                                           rr, ce1, res2);
  rownorm_kernel<<<512, 256, 0, stream>>>(res2, rr);
  quantize_kernel<<<512, 256, 0, stream>>>(res2, cb + (size_t)2 * 2048 * 256, nE + 4096,
                                           rr, ce2, res3);
  rownorm_kernel<<<512, 256, 0, stream>>>(res3, rr);
  quantize_kernel<<<512, 256, 0, stream>>>(res3, cb + (size_t)3 * 2048 * 256, nE + 6144,
                                           rr, ce3, nullptr);

  // decoder (L0 fuses zq = ((ce0+ce1)+ce2)+ce3 in the A prologue)
  gemm64<3, 1><<<dim3(4, 512), 256, 0, stream>>>(ce0, d_w0, d_b0, ce1, ce2, ce3,
                                                 g1, psum, psq, 256, 256);
  bnprep_kernel<<<1, 256, 0, stream>>>(psum, psq, d_g0, d_bt0, d0a, d0c, 256);
  gemm64<1, 1><<<dim3(2, 512), 256, 0, stream>>>(g1, d_w1, d_b1, d0a, d0c, nullptr,
                                                 g0, psum, psq, 256, 128);
  bnprep_kernel<<<1, 256, 0, stream>>>(psum, psq, d_g1, d_bt1, d1a, d1c, 128);
  gemm64<1, 0><<<dim3(1, 512), 256, 0, stream>>>(g0, d_w2, d_b2, d1a, d1c, nullptr,
                                                 xhat, nullptr, nullptr, 128, 64);
}